// Round 5
// baseline (268.602 us; speedup 1.0000x reference)
//
#include <hip/hip_runtime.h>
#include <hip/hip_bf16.h>
#include <stdint.h>

#define N_REP 8
#define BATCH 32
#define NIN   128
#define NOUT  128
#define EDIM  1024
#define MDIM  130

typedef __attribute__((ext_vector_type(8))) short short8;
typedef __attribute__((ext_vector_type(4))) float f32x4;

__device__ __forceinline__ unsigned short f2bf(float f) {
    union { float f; uint32_t u; } v;
    v.f = f;
    uint32_t u = v.u;
    uint32_t r = u + 0x7fffu + ((u >> 16) & 1u);   // RNE
    return (unsigned short)(r >> 16);
}

__device__ __forceinline__ uint32_t pk2bf(float lo, float hi) {
    __hip_bfloat162 h = __float22bfloat162_rn(make_float2(lo, hi)); // .x -> low16
    uint32_t d;
    __builtin_memcpy(&d, &h, 4);
    return d;
}

// One wave per (n,o). m parallel across lanes: m = lane, lane+64, (lane<2: 128+lane).
// Emits S[n][o][m] = W*sign (bf16, K-minor) and bias[n][o] = sum Wneg(m<128) + Wpos(m=128).
__global__ __launch_bounds__(64)
void prep_kernel(const float* __restrict__ theta,
                 const float* __restrict__ noise,
                 unsigned short* __restrict__ Sg,
                 float* __restrict__ biasg) {
    const int n = blockIdx.x >> 7;
    const int o = blockIdx.x & 127;
    const int lane = threadIdx.x;

    const float* nb = noise + (size_t)n * MDIM * NOUT + o;
    auto tn_at = [&](int m) -> float {
        float t = theta[m * NOUT + o];
        t = fminf(fmaxf(t, -1.f), 1.f);
        if (fabsf(t) < 0.01f) t = 0.f;
        return t * fmaf(nb[m * NOUT], 0.2f, 0.9f);
    };

    const float t0 = tn_at(lane);
    const float t1 = tn_at(lane + 64);
    const float t2 = (lane < 2) ? tn_at(128 + lane) : 0.f;

    float s = fabsf(t0) + fabsf(t1) + fabsf(t2);
#pragma unroll
    for (int d = 1; d < 64; d <<= 1) s += __shfl_xor(s, d, 64);
    const float inv = 1.f / (s + 1e-10f);

    const float w0 = fabsf(t0) * inv, w1 = fabsf(t1) * inv;
    unsigned short* srow = Sg + ((size_t)n * NOUT + o) * NIN;
    srow[lane]      = f2bf(t0 >= 0.f ? w0 : -w0);
    srow[lane + 64] = f2bf(t1 >= 0.f ? w1 : -w1);

    float b = (t0 < 0.f ? w0 : 0.f) + (t1 < 0.f ? w1 : 0.f);
    if (lane == 0 && t2 >= 0.f) b += fabsf(t2) * inv;   // ones-column positive part
#pragma unroll
    for (int d = 1; d < 64; d <<= 1) b += __shfl_xor(b, d, 64);
    if (lane == 0) biasg[n * NOUT + o] = b;
}

// out[nb][o][e] = tanh-act( sum_m a[nb][m][e] * S[n][o][m] + bias[n][o] ).
// NO LDS, NO barriers: A-fragments loaded DIRECTLY from global into registers.
// Per wave-instr the "strided" fragment load is 4 x 64B fully-used segments
// (r spans 16 consecutive e; fe=0/1 completes each 128B line; e-tiles 128B
// aligned) -> zero overfetch. Each wave = independent [o=128][e=32] tile, a
// read exactly once device-wide; S (32KB/n) reloaded per-ks from hot L2.
// Loads spread across the whole wave lifetime -> reads continuously in
// flight (the 4 prior LDS/DMA variants all phase-locked at ~2 TB/s).
__global__ __launch_bounds__(256, 3)
void gemm_kernel(const float* __restrict__ a,
                 const unsigned short* __restrict__ Sg,
                 const float* __restrict__ biasg,
                 const float* __restrict__ eta,
                 float* __restrict__ out) {
    const int bid  = blockIdx.x;
    const int tid  = threadIdx.x;
    const int lane = tid & 63;
    const int wv   = tid >> 6;                      // 4 independent waves over e
    const int r    = lane & 15;
    const int q    = lane >> 4;
    const int nb   = bid >> 3;                      // n*B + b
    const int n    = nb >> 5;
    const int e0w  = (((bid & 7) << 2) | wv) << 5;  // wave's 32-wide e-tile base

    const float* abase = a + (size_t)nb * (NIN * EDIM) + e0w + r;

    // eta scalars forced into VGPRs: avoids two-SGPR VOP3 (constant-bus violation)
    float e0 = eta[0], e1 = eta[1], e2 = eta[2], e3 = eta[3];
    asm volatile("" : "+v"(e0), "+v"(e1), "+v"(e2), "+v"(e3));

    float bl[8];
#pragma unroll
    for (int fo = 0; fo < 8; ++fo)
        bl[fo] = biasg[n * NOUT + (fo << 4) + r];

    f32x4 acc[8][2];                                // [fo][fe]: o=128 x e=32
#pragma unroll
    for (int fo = 0; fo < 8; ++fo)
#pragma unroll
        for (int fe = 0; fe < 2; ++fe)
            acc[fo][fe] = (f32x4){0.f, 0.f, 0.f, 0.f};

    const unsigned short* sbase = Sg + ((size_t)(n * NOUT) << 7) + (q << 3);

#pragma unroll
    for (int ks = 0; ks < 4; ++ks) {
        // A-fragments direct from global: m = ks*32 + q*8 + j, e = e0w + fe*16 + r
        float av[2][8];
#pragma unroll
        for (int fe = 0; fe < 2; ++fe)
#pragma unroll
            for (int j = 0; j < 8; ++j)
                av[fe][j] = abase[(size_t)((ks << 5) + (q << 3) + j) * EDIM + (fe << 4)];

        // S fragments (B-operand): 16B contiguous, L2-hot (32 KiB per n)
        short8 sf[8];
#pragma unroll
        for (int fo = 0; fo < 8; ++fo)
            sf[fo] = *(const short8*)(sbase + ((size_t)((fo << 4) + r) << 7) + (ks << 5));

        short8 af[2];
#pragma unroll
        for (int fe = 0; fe < 2; ++fe) {
            uint32_t d[4];
#pragma unroll
            for (int t = 0; t < 4; ++t)
                d[t] = pk2bf(av[fe][2 * t], av[fe][2 * t + 1]);
            __builtin_memcpy(&af[fe], d, 16);
        }

#pragma unroll
        for (int fo = 0; fo < 8; ++fo)
#pragma unroll
            for (int fe = 0; fe < 2; ++fe)
                acc[fo][fe] = __builtin_amdgcn_mfma_f32_16x16x32_bf16(
                    af[fe], sf[fo], acc[fo][fe], 0, 0, 0);
    }

    // ---- epilogue: bias + printed tanh; C/D: col(r)=o, row(q*4+i)=e -> float4 ----
    float* obase = out + (size_t)nb * (NOUT * EDIM) + e0w;
#pragma unroll
    for (int fo = 0; fo < 8; ++fo) {
        float* orow = obase + (size_t)((fo << 4) + r) * EDIM;
        const float bv = bl[fo];
#pragma unroll
        for (int fe = 0; fe < 2; ++fe) {
            f32x4 res;
#pragma unroll
            for (int i = 0; i < 4; ++i) {
                const float z = acc[fo][fe][i] + bv;
                const float y = (z - e2) * e3;
                const float ex = __expf(2.f * y);
                const float th = 1.f - 2.f * __builtin_amdgcn_rcpf(ex + 1.f);
                res[i] = fmaf(e1, th, e0);
            }
            *(f32x4*)(orow + (fe << 4) + (q << 2)) = res;
        }
    }
}

extern "C" void kernel_launch(void* const* d_in, const int* in_sizes, int n_in,
                              void* d_out, int out_size, void* d_ws, size_t ws_size,
                              hipStream_t stream) {
    const float* a     = (const float*)d_in[0];
    const float* theta = (const float*)d_in[1];
    const float* noise = (const float*)d_in[2];
    const float* eta   = (const float*)d_in[3];
    float* out = (float*)d_out;

    unsigned short* Sg = (unsigned short*)d_ws;      // 8*128*128 bf16 = 256 KiB
    float* biasg = (float*)((char*)d_ws + (size_t)N_REP * NOUT * NIN * sizeof(unsigned short));

    prep_kernel<<<N_REP * NOUT, 64, 0, stream>>>(theta, noise, Sg, biasg);
    gemm_kernel<<<N_REP * BATCH * 8, 256, 0, stream>>>(a, Sg, biasg, eta, out);
}